// Round 9
// baseline (78.718 us; speedup 1.0000x reference)
//
#include <hip/hip_runtime.h>

#define BATCH   2048
#define IN_DIM  16384
#define OUT_DIM 16384
#define NGATES  16
#define ROWS_PER_BLOCK 8
#define NBLK (BATCH / ROWS_PER_BLOCK)   // 256 blocks = 1 per CU

typedef float    f32x4 __attribute__((ext_vector_type(4)));
typedef _Float16 f16x4 __attribute__((ext_vector_type(4)));
typedef _Float16 f16x8 __attribute__((ext_vector_type(8)));

// COEFF[16][4] from the reference, hard-coded.
__constant__ float c_coeff[NGATES][4] = {
    {0, 0, 0, 0},  {0, 0, 0, 1},  {0, 1, 0, -1}, {0, 1, 0, 0},
    {0, 0, 1, -1}, {0, 0, 1, 0},  {0, 1, 1, -2}, {0, 1, 1, -1},
    {1, -1, -1, 1},{1, -1, -1, 2},{1, 0, -1, 0}, {1, 0, -1, 1},
    {1, -1, 0, 0}, {1, -1, 0, 1}, {1, 0, 0, -1}, {1, 0, 0, 0}
};

// Kernel 1: per output column j, fold softmax(weights[j,:]) @ COEFF into
// W[j] stored as f16x4 (8 B), and pack gather indices into one uint32.
__global__ __launch_bounds__(256) void prep_kernel(
    const float* __restrict__ weights,
    const int*   __restrict__ idx_a,
    const int*   __restrict__ idx_b,
    f16x4*       __restrict__ Wh,
    unsigned*    __restrict__ Ipk)
{
    int j = blockIdx.x * blockDim.x + threadIdx.x;
    if (j >= OUT_DIM) return;

    const float4* wrow = reinterpret_cast<const float4*>(weights + (size_t)j * NGATES);
    float v[NGATES];
    float4 q0 = wrow[0], q1 = wrow[1], q2 = wrow[2], q3 = wrow[3];
    v[0]=q0.x; v[1]=q0.y; v[2]=q0.z; v[3]=q0.w;
    v[4]=q1.x; v[5]=q1.y; v[6]=q1.z; v[7]=q1.w;
    v[8]=q2.x; v[9]=q2.y; v[10]=q2.z; v[11]=q2.w;
    v[12]=q3.x; v[13]=q3.y; v[14]=q3.z; v[15]=q3.w;

    float m = v[0];
#pragma unroll
    for (int g = 1; g < NGATES; ++g) m = fmaxf(m, v[g]);
    float s = 0.f;
#pragma unroll
    for (int g = 0; g < NGATES; ++g) { v[g] = expf(v[g] - m); s += v[g]; }
    float inv = 1.0f / s;

    float c0 = 0.f, c1 = 0.f, c2 = 0.f, c3 = 0.f;
#pragma unroll
    for (int g = 0; g < NGATES; ++g) {
        c0 += v[g] * c_coeff[g][0];
        c1 += v[g] * c_coeff[g][1];
        c2 += v[g] * c_coeff[g][2];
        c3 += v[g] * c_coeff[g][3];
    }
    f16x4 h;
    h.x = (_Float16)(c0 * inv); h.y = (_Float16)(c1 * inv);
    h.z = (_Float16)(c2 * inv); h.w = (_Float16)(c3 * inv);
    Wh[j] = h;
    Ipk[j] = (unsigned)idx_a[j] | ((unsigned)idx_b[j] << 16);   // both < 16384
}

// Async DMA stage of one 64 KB f32 row: 4 x global_load_lds(16B) per thread.
// Consumes ZERO VGPRs (the R7/R3 spill failure mode is structurally
// impossible). LDS dest per wave = uniform base + lane*16 (linear), matching
// the hardware constraint.
__device__ __forceinline__ void stage_row_async(const float* __restrict__ xrow,
                                                float* lbuf, int tid)
{
#pragma unroll
    for (int kk = 0; kk < 4; ++kk) {
        __builtin_amdgcn_global_load_lds(
            (const __attribute__((address_space(1))) void*)(xrow + tid * 4 + kk * 4096),
            (__attribute__((address_space(3))) void*)(lbuf + tid * 4 + kk * 4096),
            16, 0, 0);
    }
}

// Compute one row's outputs (4 groups of 4 per thread at 1024 threads) with a
// depth-1 idx/W prefetch pipeline. rowf = f32 row in LDS.
__device__ __forceinline__ void compute_row(
    const float* __restrict__ rowf,
    const f16x8* __restrict__ Wh8,
    const uint4* __restrict__ Ipk4,
    float* __restrict__ orow, int tid)
{
    uint4 qc = Ipk4[tid];
    f16x8 wa = Wh8[(size_t)tid * 2];
    f16x8 wb = Wh8[(size_t)tid * 2 + 1];
    f32x4* o4 = reinterpret_cast<f32x4*>(orow);

#pragma unroll
    for (int k = 0; k < OUT_DIM / 4 / 1024; ++k) {    // 4 groups
        uint4 qn;  f16x8 wan, wbn;
        if (k + 1 < OUT_DIM / 4 / 1024) {
            const int j4n = tid + (k + 1) * 1024;
            qn  = Ipk4[j4n];
            wan = Wh8[(size_t)j4n * 2];
            wbn = Wh8[(size_t)j4n * 2 + 1];
        }

        float a0 = rowf[qc.x & 0xFFFFu], b0 = rowf[qc.x >> 16];
        float a1 = rowf[qc.y & 0xFFFFu], b1 = rowf[qc.y >> 16];
        float a2 = rowf[qc.z & 0xFFFFu], b2 = rowf[qc.z >> 16];
        float a3 = rowf[qc.w & 0xFFFFu], b3 = rowf[qc.w >> 16];

        f32x4 res;
        res.x = (float)wa[0] + (float)wa[1] * a0 + (float)wa[2] * b0 + (float)wa[3] * (a0 * b0);
        res.y = (float)wa[4] + (float)wa[5] * a1 + (float)wa[6] * b1 + (float)wa[7] * (a1 * b1);
        res.z = (float)wb[0] + (float)wb[1] * a2 + (float)wb[2] * b2 + (float)wb[3] * (a2 * b2);
        res.w = (float)wb[4] + (float)wb[5] * a3 + (float)wb[6] * b3 + (float)wb[7] * (a3 * b3);
        __builtin_nontemporal_store(res, &o4[tid + k * 1024]);

        qc = qn; wa = wan; wb = wbn;
    }
}

// Kernel 2: 256 blocks x 1024 threads, 8 rows/block, 2 x 64 KB f32 ping-pong
// LDS (128 KB -> 1 block/CU, 16 waves). Row r+1 streams into the idle buffer
// via zero-VGPR async DMA during ALL of row r's compute; one vmcnt(0) +
// s_barrier per row. One prologue bubble per block instead of 8.
__global__ __launch_bounds__(1024, 2) void logic_row_kernel(
    const float* __restrict__ x,
    const f16x8* __restrict__ Wh8,
    const uint4* __restrict__ Ipk4,
    float*       __restrict__ out)
{
    __shared__ float buf[2][IN_DIM];   // 128 KB
    const int tid = threadIdx.x;
    const int r0  = blockIdx.x * ROWS_PER_BLOCK;

    // Prologue: stage row 0, drain, barrier.
    stage_row_async(x + (size_t)r0 * IN_DIM, buf[0], tid);
    asm volatile("s_waitcnt vmcnt(0)" ::: "memory");
    __builtin_amdgcn_s_barrier();

    for (int r = 0; r < ROWS_PER_BLOCK; ++r) {
        // Issue next row's DMA into the other buffer; it streams from
        // HBM/L3 under this row's entire compute phase.
        if (r + 1 < ROWS_PER_BLOCK)
            stage_row_async(x + (size_t)(r0 + r + 1) * IN_DIM, buf[(r + 1) & 1], tid);

        compute_row(buf[r & 1], Wh8, Ipk4, out + (size_t)(r0 + r) * OUT_DIM, tid);

        // Drain this wave's VMEM (stage DMA + stores), then workgroup barrier:
        // next iteration's buffer is fully written and safe to read.
        asm volatile("s_waitcnt vmcnt(0)" ::: "memory");
        __builtin_amdgcn_s_barrier();
    }
}

extern "C" void kernel_launch(void* const* d_in, const int* in_sizes, int n_in,
                              void* d_out, int out_size, void* d_ws, size_t ws_size,
                              hipStream_t stream) {
    const float* x       = (const float*)d_in[0];
    const float* weights = (const float*)d_in[1];
    const int*   idx_a   = (const int*)d_in[2];
    const int*   idx_b   = (const int*)d_in[3];
    float* out = (float*)d_out;

    // Workspace layout: Wh (OUT_DIM f16x4 = 128 KB), Ipk (OUT_DIM uint = 64 KB)
    f16x4*    Wh  = (f16x4*)d_ws;
    unsigned* Ipk = (unsigned*)((char*)d_ws + (size_t)OUT_DIM * sizeof(f16x4));

    prep_kernel<<<(OUT_DIM + 255) / 256, 256, 0, stream>>>(weights, idx_a, idx_b, Wh, Ipk);
    logic_row_kernel<<<NBLK, 1024, 0, stream>>>(x, (const f16x8*)Wh, (const uint4*)Ipk, out);
}

// Round 10
// 52.529 us; speedup vs baseline: 1.4986x; 1.4986x over previous
//
#include <hip/hip_runtime.h>

#define BATCH   2048
#define IN_DIM  16384
#define OUT_DIM 16384
#define NGATES  16

typedef float    f32x4 __attribute__((ext_vector_type(4)));
typedef _Float16 f16x4 __attribute__((ext_vector_type(4)));
typedef _Float16 f16x8 __attribute__((ext_vector_type(8)));

// COEFF[16][4] from the reference, hard-coded.
__constant__ float c_coeff[NGATES][4] = {
    {0, 0, 0, 0},  {0, 0, 0, 1},  {0, 1, 0, -1}, {0, 1, 0, 0},
    {0, 0, 1, -1}, {0, 0, 1, 0},  {0, 1, 1, -2}, {0, 1, 1, -1},
    {1, -1, -1, 1},{1, -1, -1, 2},{1, 0, -1, 0}, {1, 0, -1, 1},
    {1, -1, 0, 0}, {1, -1, 0, 1}, {1, 0, 0, -1}, {1, 0, 0, 0}
};

// Kernel 1: per output column j, fold softmax(weights[j,:]) @ COEFF into
// W[j] stored as f16x4 (8 B), and pack both gather indices as BYTE offsets
// into the f16 row (idx*2, still < 32768 -> fits 16 bits each).
__global__ __launch_bounds__(256) void prep_kernel(
    const float* __restrict__ weights,
    const int*   __restrict__ idx_a,
    const int*   __restrict__ idx_b,
    f16x4*       __restrict__ Wh,
    unsigned*    __restrict__ Ipk)
{
    int j = blockIdx.x * blockDim.x + threadIdx.x;
    if (j >= OUT_DIM) return;

    const float4* wrow = reinterpret_cast<const float4*>(weights + (size_t)j * NGATES);
    float v[NGATES];
    float4 q0 = wrow[0], q1 = wrow[1], q2 = wrow[2], q3 = wrow[3];
    v[0]=q0.x; v[1]=q0.y; v[2]=q0.z; v[3]=q0.w;
    v[4]=q1.x; v[5]=q1.y; v[6]=q1.z; v[7]=q1.w;
    v[8]=q2.x; v[9]=q2.y; v[10]=q2.z; v[11]=q2.w;
    v[12]=q3.x; v[13]=q3.y; v[14]=q3.z; v[15]=q3.w;

    float m = v[0];
#pragma unroll
    for (int g = 1; g < NGATES; ++g) m = fmaxf(m, v[g]);
    float s = 0.f;
#pragma unroll
    for (int g = 0; g < NGATES; ++g) { v[g] = expf(v[g] - m); s += v[g]; }
    float inv = 1.0f / s;

    float c0 = 0.f, c1 = 0.f, c2 = 0.f, c3 = 0.f;
#pragma unroll
    for (int g = 0; g < NGATES; ++g) {
        c0 += v[g] * c_coeff[g][0];
        c1 += v[g] * c_coeff[g][1];
        c2 += v[g] * c_coeff[g][2];
        c3 += v[g] * c_coeff[g][3];
    }
    f16x4 h;
    h.x = (_Float16)(c0 * inv); h.y = (_Float16)(c1 * inv);
    h.z = (_Float16)(c2 * inv); h.w = (_Float16)(c3 * inv);
    Wh[j] = h;
    Ipk[j] = ((unsigned)idx_a[j] << 1) | ((unsigned)idx_b[j] << 17);  // byte offsets
}

// Kernel 2: R6's winning shape (2048 blocks x 512 threads, 1 row/block,
// 32 KB f16 LDS row -> 4 blocks/CU = 32 waves), with the idx/W L2 stream
// pipelined at DEPTH 2: L2 latency (~200-300 cy) > one group's compute
// (~200 cy), so depth-1 stalled every group. Indices are pre-scaled byte
// offsets (no shift on the 16 gather address calcs). Register plan:
// 3 live stages x 12 VGPR + gathers + misc ~ 56 <= 64 cap (no spill).
__global__ __launch_bounds__(512, 8) void logic_row_kernel(
    const float* __restrict__ x,
    const f16x8* __restrict__ Wh8,
    const uint4* __restrict__ Ipk4,
    float*       __restrict__ out)
{
    __shared__ _Float16 rowh[IN_DIM];   // 32 KB
    const int tid = threadIdx.x;
    const int i   = blockIdx.x;

    // --- Stage: f32x4 coalesced load -> f16x4 -> LDS ---
    const f32x4* xr  = reinterpret_cast<const f32x4*>(x + (size_t)i * IN_DIM);
    f16x4*       rhw = reinterpret_cast<f16x4*>(rowh);
#pragma unroll
    for (int k = 0; k < IN_DIM / 4 / 512; ++k) {      // 8 chunks
        f32x4 v = xr[tid + k * 512];
        f16x4 h;
        h.x = (_Float16)v.x; h.y = (_Float16)v.y;
        h.z = (_Float16)v.z; h.w = (_Float16)v.w;
        rhw[tid + k * 512] = h;
    }

    // Prefetch groups 0 and 1 before the barrier (L2 latency hides under
    // the stage drain).
    uint4 qA  = Ipk4[tid];
    f16x8 waA = Wh8[(size_t)tid * 2];
    f16x8 wbA = Wh8[(size_t)tid * 2 + 1];
    uint4 qB  = Ipk4[tid + 512];
    f16x8 waB = Wh8[(size_t)(tid + 512) * 2];
    f16x8 wbB = Wh8[(size_t)(tid + 512) * 2 + 1];

    __syncthreads();

    const char* rowb = reinterpret_cast<const char*>(rowh);
    f32x4* o4 = reinterpret_cast<f32x4*>(out + (size_t)i * OUT_DIM);

#pragma unroll
    for (int k = 0; k < OUT_DIM / 4 / 512; ++k) {     // 8 groups of 4 outputs
        // Prefetch group k+2 (independent of this group's chain).
        uint4 qn;  f16x8 wan, wbn;
        if (k + 2 < OUT_DIM / 4 / 512) {
            const int j4n = tid + (k + 2) * 512;
            qn  = Ipk4[j4n];
            wan = Wh8[(size_t)j4n * 2];
            wbn = Wh8[(size_t)j4n * 2 + 1];
        }

        // Gathers: packed halves ARE byte offsets into the f16 row.
        float a0 = (float)*(const _Float16*)(rowb + (qA.x & 0xFFFFu));
        float b0 = (float)*(const _Float16*)(rowb + (qA.x >> 16));
        float a1 = (float)*(const _Float16*)(rowb + (qA.y & 0xFFFFu));
        float b1 = (float)*(const _Float16*)(rowb + (qA.y >> 16));
        float a2 = (float)*(const _Float16*)(rowb + (qA.z & 0xFFFFu));
        float b2 = (float)*(const _Float16*)(rowb + (qA.z >> 16));
        float a3 = (float)*(const _Float16*)(rowb + (qA.w & 0xFFFFu));
        float b3 = (float)*(const _Float16*)(rowb + (qA.w >> 16));

        f32x4 res;
        res.x = (float)waA[0] + (float)waA[1] * a0 + (float)waA[2] * b0 + (float)waA[3] * (a0 * b0);
        res.y = (float)waA[4] + (float)waA[5] * a1 + (float)waA[6] * b1 + (float)waA[7] * (a1 * b1);
        res.z = (float)wbA[0] + (float)wbA[1] * a2 + (float)wbA[2] * b2 + (float)wbA[3] * (a2 * b2);
        res.w = (float)wbA[4] + (float)wbA[5] * a3 + (float)wbA[6] * b3 + (float)wbA[7] * (a3 * b3);
        __builtin_nontemporal_store(res, &o4[tid + k * 512]);

        // Rotate the pipeline.
        qA = qB; waA = waB; wbA = wbB;
        qB = qn; waB = wan; wbB = wbn;
    }
}

extern "C" void kernel_launch(void* const* d_in, const int* in_sizes, int n_in,
                              void* d_out, int out_size, void* d_ws, size_t ws_size,
                              hipStream_t stream) {
    const float* x       = (const float*)d_in[0];
    const float* weights = (const float*)d_in[1];
    const int*   idx_a   = (const int*)d_in[2];
    const int*   idx_b   = (const int*)d_in[3];
    float* out = (float*)d_out;

    // Workspace layout: Wh (OUT_DIM f16x4 = 128 KB), Ipk (OUT_DIM uint = 64 KB)
    f16x4*    Wh  = (f16x4*)d_ws;
    unsigned* Ipk = (unsigned*)((char*)d_ws + (size_t)OUT_DIM * sizeof(f16x4));

    prep_kernel<<<(OUT_DIM + 255) / 256, 256, 0, stream>>>(weights, idx_a, idx_b, Wh, Ipk);
    logic_row_kernel<<<BATCH, 512, 0, stream>>>(x, (const f16x8*)Wh, (const uint4*)Ipk, out);
}

// Round 11
// 51.323 us; speedup vs baseline: 1.5338x; 1.0235x over previous
//
#include <hip/hip_runtime.h>

#define BATCH   2048
#define IN_DIM  16384
#define OUT_DIM 16384
#define NGATES  16
#define ROWS_PER_BLOCK 4
#define NBLK (BATCH / ROWS_PER_BLOCK)   // 512 blocks

typedef float    f32x4 __attribute__((ext_vector_type(4)));
typedef _Float16 f16x4 __attribute__((ext_vector_type(4)));
typedef _Float16 f16x8 __attribute__((ext_vector_type(8)));

// COEFF[16][4] from the reference, hard-coded.
__constant__ float c_coeff[NGATES][4] = {
    {0, 0, 0, 0},  {0, 0, 0, 1},  {0, 1, 0, -1}, {0, 1, 0, 0},
    {0, 0, 1, -1}, {0, 0, 1, 0},  {0, 1, 1, -2}, {0, 1, 1, -1},
    {1, -1, -1, 1},{1, -1, -1, 2},{1, 0, -1, 0}, {1, 0, -1, 1},
    {1, -1, 0, 0}, {1, -1, 0, 1}, {1, 0, 0, -1}, {1, 0, 0, 0}
};

__device__ __forceinline__ f16x4 cvt_f16x4(f32x4 v) {
    f16x4 h;
    h.x = (_Float16)v.x; h.y = (_Float16)v.y;
    h.z = (_Float16)v.z; h.w = (_Float16)v.w;
    return h;
}

// Kernel 1: per output column j, fold softmax(weights[j,:]) @ COEFF into
// W[j] stored as f16x4 (8 B), and pack gather indices into one uint32.
__global__ __launch_bounds__(256) void prep_kernel(
    const float* __restrict__ weights,
    const int*   __restrict__ idx_a,
    const int*   __restrict__ idx_b,
    f16x4*       __restrict__ Wh,
    unsigned*    __restrict__ Ipk)
{
    int j = blockIdx.x * blockDim.x + threadIdx.x;
    if (j >= OUT_DIM) return;

    const float4* wrow = reinterpret_cast<const float4*>(weights + (size_t)j * NGATES);
    float v[NGATES];
    float4 q0 = wrow[0], q1 = wrow[1], q2 = wrow[2], q3 = wrow[3];
    v[0]=q0.x; v[1]=q0.y; v[2]=q0.z; v[3]=q0.w;
    v[4]=q1.x; v[5]=q1.y; v[6]=q1.z; v[7]=q1.w;
    v[8]=q2.x; v[9]=q2.y; v[10]=q2.z; v[11]=q2.w;
    v[12]=q3.x; v[13]=q3.y; v[14]=q3.z; v[15]=q3.w;

    float m = v[0];
#pragma unroll
    for (int g = 1; g < NGATES; ++g) m = fmaxf(m, v[g]);
    float s = 0.f;
#pragma unroll
    for (int g = 0; g < NGATES; ++g) { v[g] = expf(v[g] - m); s += v[g]; }
    float inv = 1.0f / s;

    float c0 = 0.f, c1 = 0.f, c2 = 0.f, c3 = 0.f;
#pragma unroll
    for (int g = 0; g < NGATES; ++g) {
        c0 += v[g] * c_coeff[g][0];
        c1 += v[g] * c_coeff[g][1];
        c2 += v[g] * c_coeff[g][2];
        c3 += v[g] * c_coeff[g][3];
    }
    f16x4 h;
    h.x = (_Float16)(c0 * inv); h.y = (_Float16)(c1 * inv);
    h.z = (_Float16)(c2 * inv); h.w = (_Float16)(c3 * inv);
    Wh[j] = h;
    Ipk[j] = (unsigned)idx_a[j] | ((unsigned)idx_b[j] << 16);   // both < 16384
}

// Kernel 2: 512 blocks x 512 threads, 4 rows/block, 2 x 32 KB f16 ping-pong
// LDS (64 KB -> 2 blocks/CU, 16 waves). CHUNK-LEVEL interleave: next row's
// 8 f32x4 chunks are loaded INSIDE the current row's 8-group compute loop,
// one chunk per group, written to the other buffer one group later
// (write-behind, ~800 cy load landing time). Only 2 chunks (8 VGPR) live at
// once -> no spill (the R3/R7 failure). The HBM read stream is continuous
// under compute instead of bursty (the R6 residual). One barrier per row.
__global__ __launch_bounds__(512, 4) void logic_row_kernel(
    const float* __restrict__ x,
    const f16x8* __restrict__ Wh8,
    const uint4* __restrict__ Ipk4,
    float*       __restrict__ out)
{
    __shared__ _Float16 buf[2][IN_DIM];   // 2 x 32 KB
    const int tid = threadIdx.x;
    const int r0  = blockIdx.x * ROWS_PER_BLOCK;

    // Stage row 0 into buf[0].
    {
        const f32x4* xr  = reinterpret_cast<const f32x4*>(x + (size_t)r0 * IN_DIM);
        f16x4*       dst = reinterpret_cast<f16x4*>(buf[0]);
#pragma unroll
        for (int k = 0; k < 8; ++k)
            dst[tid + k * 512] = cvt_f16x4(xr[tid + k * 512]);
    }
    __syncthreads();

    for (int r = 0; r < ROWS_PER_BLOCK; ++r) {
        const _Float16* __restrict__ rowh = buf[r & 1];
        f16x4* nb = reinterpret_cast<f16x4*>(buf[(r + 1) & 1]);
        const bool more = (r + 1 < ROWS_PER_BLOCK);
        const f32x4* xn = reinterpret_cast<const f32x4*>(
            x + (size_t)(r0 + r + 1) * IN_DIM);   // only deref'd when more

        uint4 qc = Ipk4[tid];
        f16x8 wa = Wh8[(size_t)tid * 2];
        f16x8 wb = Wh8[(size_t)tid * 2 + 1];
        f32x4* o4 = reinterpret_cast<f32x4*>(out + (size_t)(r0 + r) * OUT_DIM);
        f32x4 vprev;

#pragma unroll
        for (int k = 0; k < 8; ++k) {              // 8 groups of 4 outputs
            // Embedded next-row chunk load (independent; lands under compute).
            f32x4 vcur;
            if (more) vcur = xn[tid + k * 512];

            // Depth-1 idx/W prefetch (R6's proven pattern).
            uint4 qn;  f16x8 wan, wbn;
            if (k + 1 < 8) {
                const int j4n = tid + (k + 1) * 512;
                qn  = Ipk4[j4n];
                wan = Wh8[(size_t)j4n * 2];
                wbn = Wh8[(size_t)j4n * 2 + 1];
            }

            float a0 = (float)rowh[qc.x & 0xFFFFu], b0 = (float)rowh[qc.x >> 16];
            float a1 = (float)rowh[qc.y & 0xFFFFu], b1 = (float)rowh[qc.y >> 16];
            float a2 = (float)rowh[qc.z & 0xFFFFu], b2 = (float)rowh[qc.z >> 16];
            float a3 = (float)rowh[qc.w & 0xFFFFu], b3 = (float)rowh[qc.w >> 16];

            f32x4 res;
            res.x = (float)wa[0] + (float)wa[1] * a0 + (float)wa[2] * b0 + (float)wa[3] * (a0 * b0);
            res.y = (float)wa[4] + (float)wa[5] * a1 + (float)wa[6] * b1 + (float)wa[7] * (a1 * b1);
            res.z = (float)wb[0] + (float)wb[1] * a2 + (float)wb[2] * b2 + (float)wb[3] * (a2 * b2);
            res.w = (float)wb[4] + (float)wb[5] * a3 + (float)wb[6] * b3 + (float)wb[7] * (a3 * b3);
            __builtin_nontemporal_store(res, &o4[tid + k * 512]);

            // Write-behind: chunk k-1 of the next row into the idle buffer.
            if (more && k > 0) nb[tid + (k - 1) * 512] = cvt_f16x4(vprev);
            vprev = vcur;

            qc = qn; wa = wan; wb = wbn;
        }
        if (more) nb[tid + 7 * 512] = cvt_f16x4(vprev);

        __syncthreads();   // next buffer fully written; row r reads done
    }
}

extern "C" void kernel_launch(void* const* d_in, const int* in_sizes, int n_in,
                              void* d_out, int out_size, void* d_ws, size_t ws_size,
                              hipStream_t stream) {
    const float* x       = (const float*)d_in[0];
    const float* weights = (const float*)d_in[1];
    const int*   idx_a   = (const int*)d_in[2];
    const int*   idx_b   = (const int*)d_in[3];
    float* out = (float*)d_out;

    // Workspace layout: Wh (OUT_DIM f16x4 = 128 KB), Ipk (OUT_DIM uint = 64 KB)
    f16x4*    Wh  = (f16x4*)d_ws;
    unsigned* Ipk = (unsigned*)((char*)d_ws + (size_t)OUT_DIM * sizeof(f16x4));

    prep_kernel<<<(OUT_DIM + 255) / 256, 256, 0, stream>>>(weights, idx_a, idx_b, Wh, Ipk);
    logic_row_kernel<<<NBLK, 512, 0, stream>>>(x, (const f16x8*)Wh, (const uint4*)Ipk, out);
}